// Round 18
// baseline (84.610 us; speedup 1.0000x reference)
//
#include <hip/hip_runtime.h>
#include <math.h>

// TripletHard B=8192 D=128 NC=256. Round-18 = r16's proven per-block loop
// with an OVERSUBSCRIBED grid: 1024 main (32 i x 32 g, 8x32-col tiles) + 256
// pos = 1280 blocks at 3/CU. r16's 768-block grid left the 3rd CU slot empty
// after pos drained (~2 us) -> bulk ran at 8 waves/CU; with 1280 blocks the
// scheduler backfills and keeps ~12 waves/CU until the tail.
//   prep : fp32->bf16 (RNE), K-major fbT, lsq=(sq,lblbits) of rounded values.
//   work : [0,1024): neg-only diff-class min, wave tile 64x32 (mf=4, nf=2),
//          A-frags resident, B via LDS dbuf (8 KB tiles).
//          [1024,1280): per-class Gram -> 2nd-smallest same-class d2.
//   merge: combine 32 n1 slices + pos_d2 -> mean hinge (device atomics).
// fbT8[kc*8192 + row] = features[row][kc*8..kc*8+7], kc=0..15.

#define BN 8192
#define MARGIN_F 1.0f
#define EPS_F 1e-5f

typedef __attribute__((ext_vector_type(8))) short short8;
typedef __attribute__((ext_vector_type(4))) float floatx4;

__device__ __forceinline__ unsigned short bf16_rne(float x, float& r) {
    unsigned u = __float_as_uint(x);
    u += 0x7FFF + ((u >> 16) & 1);
    unsigned short h = (unsigned short)(u >> 16);
    r = __uint_as_float(((unsigned)h) << 16);
    return h;
}

// 8 threads/row (256 blocks): bf16 convert, K-major write, lsq=(sq, lblbits)
// from ROUNDED values. Also zero-inits g_acc/counter.
__global__ __launch_bounds__(256) void prep_kernel(const float* __restrict__ f,
                                                   const int* __restrict__ lbl,
                                                   short8* __restrict__ fbT,
                                                   float2* __restrict__ lsq,
                                                   float* __restrict__ g_acc,
                                                   unsigned* __restrict__ counter) {
    int gid = blockIdx.x * 256 + threadIdx.x;  // 0..65535
    if (gid == 0) { *g_acc = 0.f; *counter = 0u; }
    int row = gid >> 3, part = gid & 7;
    const float4* f4 = (const float4*)f + (size_t)row * 32 + part * 4;
    float s = 0.f;
#pragma unroll
    for (int cc = 0; cc < 2; ++cc) {  // chunk kc = part*2 + cc
        float4 v0 = f4[cc * 2], v1 = f4[cc * 2 + 1];
        float r0, r1, r2, r3, r4, r5, r6, r7;
        short8 o;
        o[0] = (short)bf16_rne(v0.x, r0);
        o[1] = (short)bf16_rne(v0.y, r1);
        o[2] = (short)bf16_rne(v0.z, r2);
        o[3] = (short)bf16_rne(v0.w, r3);
        o[4] = (short)bf16_rne(v1.x, r4);
        o[5] = (short)bf16_rne(v1.y, r5);
        o[6] = (short)bf16_rne(v1.z, r6);
        o[7] = (short)bf16_rne(v1.w, r7);
        fbT[(size_t)(part * 2 + cc) * BN + row] = o;
        s += r0 * r0 + r1 * r1 + r2 * r2 + r3 * r3 +
             r4 * r4 + r5 * r5 + r6 * r6 + r7 * r7;
    }
    s += __shfl_xor(s, 1, 8);
    s += __shfl_xor(s, 2, 8);
    s += __shfl_xor(s, 4, 8);
    if (part == 0) {
        float2 p;
        p.x = s;
        p.y = __int_as_float(lbl[row]);
        lsq[row] = p;
    }
}

// Stage one 32-col B-tile (16 chunks x 32 cols = 8 KB) into LDS: each wave
// issues 2 global_load_lds(16B). LDS dest is wave-uniform; HW adds lane*16.
// Layout: tile[kc*32 + col], kc = lane>>5 within each 64-slot instr.
__device__ __forceinline__ void stage_tile(const short8* __restrict__ fbT,
                                           short8* tile, int j0, int wv, int lane) {
#pragma unroll
    for (int it = 0; it < 2; ++it) {
        int s = wv * 128 + it * 64;  // wave-uniform slot base
        int kc = (s >> 5) + (lane >> 5);
        int col = lane & 31;
        const short8* g = fbT + ((size_t)kc * BN + j0 + col);
        __builtin_amdgcn_global_load_lds(
            (const __attribute__((address_space(1))) void*)g,
            (__attribute__((address_space(3))) void*)(tile + s),
            16, 0, 0);
    }
}

// Fused work kernel. Blocks [0,1024): main. [1024,1280): pos (backfill).
__global__ __launch_bounds__(256, 3) void work_kernel(const short8* __restrict__ fbT,
                                                      const int* __restrict__ lbl,
                                                      const float2* __restrict__ lsq,
                                                      float* __restrict__ part,
                                                      float* __restrict__ pos_d2) {
    const int t = threadIdx.x;
    const int lane = t & 63;
    const int wv = t >> 6;
    const int q = lane >> 4, c = lane & 15;
    const int bid = blockIdx.x;

    if (bid >= 1024) {
        // ---------------- pos path: per-class 2nd-smallest same-class d2 ---
        __shared__ int midx[256];
        __shared__ int cnt;
        const int cls = bid - 1024;
        if (t == 0) cnt = 0;
        __syncthreads();
        // vectorized scan: 4 labels per thread per round, 8 rounds
        const int4* lbl4 = (const int4*)lbl;
        for (int r4 = t; r4 < BN / 4; r4 += 256) {
            int4 L = lbl4[r4];
            if (L.x == cls) { int p = atomicAdd(&cnt, 1); if (p < 256) midx[p] = r4 * 4; }
            if (L.y == cls) { int p = atomicAdd(&cnt, 1); if (p < 256) midx[p] = r4 * 4 + 1; }
            if (L.z == cls) { int p = atomicAdd(&cnt, 1); if (p < 256) midx[p] = r4 * 4 + 2; }
            if (L.w == cls) { int p = atomicAdd(&cnt, 1); if (p < 256) midx[p] = r4 * 4 + 3; }
        }
        __syncthreads();
        int n = cnt < 256 ? cnt : 256;
        if (n == 0) return;
        if (t < 256 && t >= n) midx[t] = midx[0];  // pad
        __syncthreads();

        const int ng = (n + 15) >> 4;  // 16-row groups; wave wv takes ig = wv, wv+4, ...
        for (int ig = wv; ig < ng; ig += 4) {
            short8 a[4];
            int arow = midx[ig * 16 + c];
#pragma unroll
            for (int ks = 0; ks < 4; ++ks)
                a[ks] = fbT[(size_t)(ks * 4 + q) * BN + arow];
            float s1[4], s2[4];
#pragma unroll
            for (int rg = 0; rg < 4; ++rg) { s1[rg] = INFINITY; s2[rg] = INFINITY; }

            for (int s = 0; s < ng; ++s) {  // 16 j-slots per step
                int jslot = s * 16 + c;
                int jrow = midx[jslot];
                short8 b[4];
#pragma unroll
                for (int ks = 0; ks < 4; ++ks)
                    b[ks] = fbT[(size_t)(ks * 4 + q) * BN + jrow];
                float sj = lsq[jrow].x;
                bool valid = (jslot < n);

                floatx4 acc = (floatx4)0.f;
#pragma unroll
                for (int ks = 0; ks < 4; ++ks)
                    acc = __builtin_amdgcn_mfma_f32_16x16x32_bf16(a[ks], b[ks], acc, 0, 0, 0);
#pragma unroll
                for (int rg = 0; rg < 4; ++rg) {
                    float v = fmaf(-2.0f, acc[rg], sj);
                    float vs = valid ? v : INFINITY;
                    s2[rg] = fminf(s2[rg], fmaxf(s1[rg], vs));
                    s1[rg] = fminf(s1[rg], vs);
                }
            }
#pragma unroll
            for (int m = 1; m < 16; m <<= 1) {
#pragma unroll
                for (int rg = 0; rg < 4; ++rg) {
                    float o1 = __shfl_xor(s1[rg], m, 16);
                    float o2 = __shfl_xor(s2[rg], m, 16);
                    float lo = fminf(s1[rg], o1);
                    float hi = fminf(fmaxf(s1[rg], o1), fminf(s2[rg], o2));
                    s1[rg] = lo; s2[rg] = hi;
                }
            }
            if (c == 0) {
#pragma unroll
                for (int rg = 0; rg < 4; ++rg) {
                    int islot = ig * 16 + q * 4 + rg;
                    if (islot < n) {
                        int row = midx[islot];
                        pos_d2[row] = lsq[row].x + s2[rg];
                    }
                }
            }
        }
        return;
    }

    // --- main path: diff-class min, wave tile 64x32 (mf=4, nf=2), 8 jt ----
    __shared__ short8 Bt[2][512];    // 2 x 8 KB, [kc*32 + col]
    __shared__ float2 lsq_sh[256];   // block's 256-col j-stripe (sq, lblbits)

    const int i0 = (bid & 31) * 256 + wv * 64;  // 32 i-blocks x 4 waves x 64 rows
    const int g = bid >> 5;  // 0..31
    const int jb = g * 256;

    stage_tile(fbT, Bt[0], jb, wv, lane);  // tile 0 in flight

    // stage the stripe's (sq,label) once: 256 float2, 1 per thread
    lsq_sh[t] = lsq[jb + t];

    short8 a[4][4];
#pragma unroll
    for (int mf = 0; mf < 4; ++mf) {
        int row = i0 + mf * 16 + c;
#pragma unroll
        for (int ks = 0; ks < 4; ++ks)
            a[mf][ks] = fbT[(size_t)(ks * 4 + q) * BN + row];
    }
    int li[4][4];
#pragma unroll
    for (int mf = 0; mf < 4; ++mf)
#pragma unroll
        for (int rg = 0; rg < 4; ++rg)
            li[mf][rg] = __float_as_int(lsq[i0 + mf * 16 + q * 4 + rg].y);

    float n1[4][4];
#pragma unroll
    for (int mf = 0; mf < 4; ++mf)
#pragma unroll
        for (int rg = 0; rg < 4; ++rg) n1[mf][rg] = INFINITY;

    __syncthreads();  // tile 0 + lsq_sh resident

    for (int jt = 0; jt < 8; ++jt) {
        const short8* cur = Bt[jt & 1];
        const int j0 = jb + jt * 32;
        // prefetch next tile NOW; it lands during this tile's compute
        if (jt < 7) stage_tile(fbT, Bt[1 - (jt & 1)], j0 + 32, wv, lane);

        int ljv[2]; float sjv[2];
#pragma unroll
        for (int nf = 0; nf < 2; ++nf) {
            float2 p = lsq_sh[jt * 32 + nf * 16 + c];  // LDS, no global latency
            sjv[nf] = p.x;
            ljv[nf] = __float_as_int(p.y);
        }

        floatx4 acc[4][2];
#pragma unroll
        for (int mf = 0; mf < 4; ++mf)
#pragma unroll
            for (int nf = 0; nf < 2; ++nf) acc[mf][nf] = (floatx4)0.f;

#pragma unroll
        for (int ks = 0; ks < 4; ++ks) {
            short8 b[2];
#pragma unroll
            for (int nf = 0; nf < 2; ++nf)
                b[nf] = cur[(ks * 4 + q) * 32 + nf * 16 + c];
#pragma unroll
            for (int mf = 0; mf < 4; ++mf)
#pragma unroll
                for (int nf = 0; nf < 2; ++nf)
                    acc[mf][nf] = __builtin_amdgcn_mfma_f32_16x16x32_bf16(
                        a[mf][ks], b[nf], acc[mf][nf], 0, 0, 0);
        }

        // neg-only epilogue: 4 ops/element
#pragma unroll
        for (int nf = 0; nf < 2; ++nf) {
#pragma unroll
            for (int mf = 0; mf < 4; ++mf)
#pragma unroll
                for (int rg = 0; rg < 4; ++rg) {
                    float v = fmaf(-2.0f, acc[mf][nf][rg], sjv[nf]);
                    float vd = (li[mf][rg] == ljv[nf]) ? INFINITY : v;
                    n1[mf][rg] = fminf(n1[mf][rg], vd);
                }
        }
        // barrier at END: stage had the whole compute to land -> drain ~free
        __syncthreads();
    }

    // min across the 16 c-lanes sharing each accumulator row
#pragma unroll
    for (int m = 1; m < 16; m <<= 1) {
#pragma unroll
        for (int mf = 0; mf < 4; ++mf)
#pragma unroll
            for (int rg = 0; rg < 4; ++rg)
                n1[mf][rg] = fminf(n1[mf][rg], __shfl_xor(n1[mf][rg], m, 16));
    }
    if (c == 0) {
#pragma unroll
        for (int mf = 0; mf < 4; ++mf)
#pragma unroll
            for (int rg = 0; rg < 4; ++rg)
                part[g * BN + i0 + mf * 16 + q * 4 + rg] = n1[mf][rg];
    }
}

// combine 32 n1 slices + pos_d2 -> hinge; atomic sum; last block writes mean
__global__ __launch_bounds__(128) void merge_kernel(const float* __restrict__ part,
                                                    const float2* __restrict__ lsq,
                                                    const float* __restrict__ pos_d2,
                                                    float* __restrict__ g_acc,
                                                    unsigned* __restrict__ counter,
                                                    float* __restrict__ out) {
    int r = blockIdx.x * 128 + threadIdx.x;
    float n = INFINITY;
#pragma unroll
    for (int k = 0; k < 32; ++k) n = fminf(n, part[k * BN + r]);
    float si = lsq[r].x;
    float pos = sqrtf(fmaxf(pos_d2[r] + EPS_F, 0.f));
    float neg = sqrtf(fmaxf(si + n + EPS_F, 0.f));
    float h = fmaxf(MARGIN_F + pos - neg, 0.f);
    __shared__ float red[2];
#pragma unroll
    for (int m = 32; m >= 1; m >>= 1) h += __shfl_down(h, m, 64);
    if ((threadIdx.x & 63) == 0) red[threadIdx.x >> 6] = h;
    __syncthreads();
    if (threadIdx.x == 0) {
        atomicAdd(g_acc, red[0] + red[1]);
        __threadfence();
        unsigned old = atomicAdd(counter, 1u);
        if (old == 63u) {
            float tot = atomicAdd(g_acc, 0.0f);
            out[0] = tot / (float)BN;
        }
    }
}

extern "C" void kernel_launch(void* const* d_in, const int* in_sizes, int n_in,
                              void* d_out, int out_size, void* d_ws, size_t ws_size,
                              hipStream_t stream) {
    const float* f = (const float*)d_in[0];
    const int* lbl = (const int*)d_in[1];
    char* ws = (char*)d_ws;
    float2* lsq = (float2*)ws;                                 // 64 KB
    short8* fbT = (short8*)(ws + 65536);                       // 2 MB
    float* part = (float*)(ws + 65536 + 2097152);              // 1 MB (32 slices)
    float* pos_d2 = (float*)(ws + 65536 + 2097152 + 1048576);  // 32 KB
    float* g_acc = (float*)(ws + 65536 + 2097152 + 1048576 + 32768);
    unsigned* counter = (unsigned*)(g_acc + 1);
    float* out = (float*)d_out;

    prep_kernel<<<256, 256, 0, stream>>>(f, lbl, fbT, lsq, g_acc, counter);
    work_kernel<<<1280, 256, 0, stream>>>(fbT, lbl, lsq, part, pos_d2);
    merge_kernel<<<64, 128, 0, stream>>>(part, lsq, pos_d2, g_acc, counter, out);
}

// Round 19
// 83.191 us; speedup vs baseline: 1.0171x; 1.0171x over previous
//
#include <hip/hip_runtime.h>
#include <math.h>

// TripletHard B=8192 D=128 NC=256. Round-19 = r16 EXACT structure with
// __launch_bounds__(256,2). r17's counters exposed VGPR_Count=84: under the
// (256,3) ~170-reg cap the compiler REMATERIALIZED the 64-VGPR A-fragment
// set from global every jt (16 hidden L2 loads/wave/jt) — the stall all the
// r15-r17 micro-fixes failed to remove. At cap ~256 the a-frags stay
// resident. Bulk occupancy is unchanged (r16's 3rd CU slot sat empty after
// pos drained anyway — r17 lesson).
//   prep : fp32->bf16 (RNE), K-major fbT, lsq=(sq,lblbits) of rounded values.
//   work : 768 blocks. [0,512): neg-only diff-class min, wave tile 64x32
//          (mf=4, nf=2), A-frags resident, B via LDS dbuf, 16 jt.
//          [512,768): per-class Gram -> 2nd-smallest same-class d2 (backfill).
//   merge: combine 16 n1 slices + pos_d2 -> mean hinge (device atomics).
// fbT8[kc*8192 + row] = features[row][kc*8..kc*8+7], kc=0..15.

#define BN 8192
#define MARGIN_F 1.0f
#define EPS_F 1e-5f

typedef __attribute__((ext_vector_type(8))) short short8;
typedef __attribute__((ext_vector_type(4))) float floatx4;

__device__ __forceinline__ unsigned short bf16_rne(float x, float& r) {
    unsigned u = __float_as_uint(x);
    u += 0x7FFF + ((u >> 16) & 1);
    unsigned short h = (unsigned short)(u >> 16);
    r = __uint_as_float(((unsigned)h) << 16);
    return h;
}

// 8 threads/row (256 blocks): bf16 convert, K-major write, lsq=(sq, lblbits)
// from ROUNDED values. Also zero-inits g_acc/counter.
__global__ __launch_bounds__(256) void prep_kernel(const float* __restrict__ f,
                                                   const int* __restrict__ lbl,
                                                   short8* __restrict__ fbT,
                                                   float2* __restrict__ lsq,
                                                   float* __restrict__ g_acc,
                                                   unsigned* __restrict__ counter) {
    int gid = blockIdx.x * 256 + threadIdx.x;  // 0..65535
    if (gid == 0) { *g_acc = 0.f; *counter = 0u; }
    int row = gid >> 3, part = gid & 7;
    const float4* f4 = (const float4*)f + (size_t)row * 32 + part * 4;
    float s = 0.f;
#pragma unroll
    for (int cc = 0; cc < 2; ++cc) {  // chunk kc = part*2 + cc
        float4 v0 = f4[cc * 2], v1 = f4[cc * 2 + 1];
        float r0, r1, r2, r3, r4, r5, r6, r7;
        short8 o;
        o[0] = (short)bf16_rne(v0.x, r0);
        o[1] = (short)bf16_rne(v0.y, r1);
        o[2] = (short)bf16_rne(v0.z, r2);
        o[3] = (short)bf16_rne(v0.w, r3);
        o[4] = (short)bf16_rne(v1.x, r4);
        o[5] = (short)bf16_rne(v1.y, r5);
        o[6] = (short)bf16_rne(v1.z, r6);
        o[7] = (short)bf16_rne(v1.w, r7);
        fbT[(size_t)(part * 2 + cc) * BN + row] = o;
        s += r0 * r0 + r1 * r1 + r2 * r2 + r3 * r3 +
             r4 * r4 + r5 * r5 + r6 * r6 + r7 * r7;
    }
    s += __shfl_xor(s, 1, 8);
    s += __shfl_xor(s, 2, 8);
    s += __shfl_xor(s, 4, 8);
    if (part == 0) {
        float2 p;
        p.x = s;
        p.y = __int_as_float(lbl[row]);
        lsq[row] = p;
    }
}

// Stage one 32-col B-tile (16 chunks x 32 cols = 8 KB) into LDS: each wave
// issues 2 global_load_lds(16B). LDS dest is wave-uniform; HW adds lane*16.
// Layout: tile[kc*32 + col], kc = lane>>5 within each 64-slot instr.
__device__ __forceinline__ void stage_tile(const short8* __restrict__ fbT,
                                           short8* tile, int j0, int wv, int lane) {
#pragma unroll
    for (int it = 0; it < 2; ++it) {
        int s = wv * 128 + it * 64;  // wave-uniform slot base
        int kc = (s >> 5) + (lane >> 5);
        int col = lane & 31;
        const short8* g = fbT + ((size_t)kc * BN + j0 + col);
        __builtin_amdgcn_global_load_lds(
            (const __attribute__((address_space(1))) void*)g,
            (__attribute__((address_space(3))) void*)(tile + s),
            16, 0, 0);
    }
}

// Fused work kernel. Blocks [0,512): main (gen-1 resident at 2/CU).
// Blocks [512,768): pos, backfill. lb(256,2): ~256-reg cap keeps a-frags
// resident (the r19 fix).
__global__ __launch_bounds__(256, 2) void work_kernel(const short8* __restrict__ fbT,
                                                      const int* __restrict__ lbl,
                                                      const float2* __restrict__ lsq,
                                                      float* __restrict__ part,
                                                      float* __restrict__ pos_d2) {
    const int t = threadIdx.x;
    const int lane = t & 63;
    const int wv = t >> 6;
    const int q = lane >> 4, c = lane & 15;
    const int bid = blockIdx.x;

    if (bid >= 512) {
        // ---------------- pos path: per-class 2nd-smallest same-class d2 ---
        __shared__ int midx[256];
        __shared__ int cnt;
        const int cls = bid - 512;
        if (t == 0) cnt = 0;
        __syncthreads();
        // vectorized scan: 4 labels per thread per round, 8 rounds
        const int4* lbl4 = (const int4*)lbl;
        for (int r4 = t; r4 < BN / 4; r4 += 256) {
            int4 L = lbl4[r4];
            if (L.x == cls) { int p = atomicAdd(&cnt, 1); if (p < 256) midx[p] = r4 * 4; }
            if (L.y == cls) { int p = atomicAdd(&cnt, 1); if (p < 256) midx[p] = r4 * 4 + 1; }
            if (L.z == cls) { int p = atomicAdd(&cnt, 1); if (p < 256) midx[p] = r4 * 4 + 2; }
            if (L.w == cls) { int p = atomicAdd(&cnt, 1); if (p < 256) midx[p] = r4 * 4 + 3; }
        }
        __syncthreads();
        int n = cnt < 256 ? cnt : 256;
        if (n == 0) return;
        if (t < 256 && t >= n) midx[t] = midx[0];  // pad
        __syncthreads();

        const int ng = (n + 15) >> 4;  // 16-row groups; wave wv takes ig = wv, wv+4, ...
        for (int ig = wv; ig < ng; ig += 4) {
            short8 a[4];
            int arow = midx[ig * 16 + c];
#pragma unroll
            for (int ks = 0; ks < 4; ++ks)
                a[ks] = fbT[(size_t)(ks * 4 + q) * BN + arow];
            float s1[4], s2[4];
#pragma unroll
            for (int rg = 0; rg < 4; ++rg) { s1[rg] = INFINITY; s2[rg] = INFINITY; }

            for (int s = 0; s < ng; ++s) {  // 16 j-slots per step
                int jslot = s * 16 + c;
                int jrow = midx[jslot];
                short8 b[4];
#pragma unroll
                for (int ks = 0; ks < 4; ++ks)
                    b[ks] = fbT[(size_t)(ks * 4 + q) * BN + jrow];
                float sj = lsq[jrow].x;
                bool valid = (jslot < n);

                floatx4 acc = (floatx4)0.f;
#pragma unroll
                for (int ks = 0; ks < 4; ++ks)
                    acc = __builtin_amdgcn_mfma_f32_16x16x32_bf16(a[ks], b[ks], acc, 0, 0, 0);
#pragma unroll
                for (int rg = 0; rg < 4; ++rg) {
                    float v = fmaf(-2.0f, acc[rg], sj);
                    float vs = valid ? v : INFINITY;
                    s2[rg] = fminf(s2[rg], fmaxf(s1[rg], vs));
                    s1[rg] = fminf(s1[rg], vs);
                }
            }
#pragma unroll
            for (int m = 1; m < 16; m <<= 1) {
#pragma unroll
                for (int rg = 0; rg < 4; ++rg) {
                    float o1 = __shfl_xor(s1[rg], m, 16);
                    float o2 = __shfl_xor(s2[rg], m, 16);
                    float lo = fminf(s1[rg], o1);
                    float hi = fminf(fmaxf(s1[rg], o1), fminf(s2[rg], o2));
                    s1[rg] = lo; s2[rg] = hi;
                }
            }
            if (c == 0) {
#pragma unroll
                for (int rg = 0; rg < 4; ++rg) {
                    int islot = ig * 16 + q * 4 + rg;
                    if (islot < n) {
                        int row = midx[islot];
                        pos_d2[row] = lsq[row].x + s2[rg];
                    }
                }
            }
        }
        return;
    }

    // --- main path: diff-class min, wave tile 64x32 (mf=4, nf=2), 16 jt ---
    __shared__ short8 Bt[2][512];    // 2 x 8 KB, [kc*32 + col]
    __shared__ float2 lsq_sh[512];   // block's j-stripe (sq, lblbits)

    const int i0 = (bid & 31) * 256 + wv * 64;  // 32 i-blocks x 4 waves x 64 rows
    const int g = bid >> 5;  // 0..15
    const int jb = g * 512;

    stage_tile(fbT, Bt[0], jb, wv, lane);  // tile 0 in flight

    // stage the whole stripe's (sq,label) once: 512 float2, 2 per thread
    lsq_sh[t] = lsq[jb + t];
    lsq_sh[t + 256] = lsq[jb + t + 256];

    short8 a[4][4];
#pragma unroll
    for (int mf = 0; mf < 4; ++mf) {
        int row = i0 + mf * 16 + c;
#pragma unroll
        for (int ks = 0; ks < 4; ++ks)
            a[mf][ks] = fbT[(size_t)(ks * 4 + q) * BN + row];
    }
    int li[4][4];
#pragma unroll
    for (int mf = 0; mf < 4; ++mf)
#pragma unroll
        for (int rg = 0; rg < 4; ++rg)
            li[mf][rg] = __float_as_int(lsq[i0 + mf * 16 + q * 4 + rg].y);

    float n1[4][4];
#pragma unroll
    for (int mf = 0; mf < 4; ++mf)
#pragma unroll
        for (int rg = 0; rg < 4; ++rg) n1[mf][rg] = INFINITY;

    __syncthreads();  // tile 0 + lsq_sh resident

    for (int jt = 0; jt < 16; ++jt) {
        const short8* cur = Bt[jt & 1];
        const int j0 = jb + jt * 32;
        // prefetch next tile NOW; it lands during this tile's compute
        if (jt < 15) stage_tile(fbT, Bt[1 - (jt & 1)], j0 + 32, wv, lane);

        int ljv[2]; float sjv[2];
#pragma unroll
        for (int nf = 0; nf < 2; ++nf) {
            float2 p = lsq_sh[jt * 32 + nf * 16 + c];  // LDS, no global latency
            sjv[nf] = p.x;
            ljv[nf] = __float_as_int(p.y);
        }

        floatx4 acc[4][2];
#pragma unroll
        for (int mf = 0; mf < 4; ++mf)
#pragma unroll
            for (int nf = 0; nf < 2; ++nf) acc[mf][nf] = (floatx4)0.f;

#pragma unroll
        for (int ks = 0; ks < 4; ++ks) {
            short8 b[2];
#pragma unroll
            for (int nf = 0; nf < 2; ++nf)
                b[nf] = cur[(ks * 4 + q) * 32 + nf * 16 + c];
#pragma unroll
            for (int mf = 0; mf < 4; ++mf)
#pragma unroll
                for (int nf = 0; nf < 2; ++nf)
                    acc[mf][nf] = __builtin_amdgcn_mfma_f32_16x16x32_bf16(
                        a[mf][ks], b[nf], acc[mf][nf], 0, 0, 0);
        }

        // neg-only epilogue: 4 ops/element
#pragma unroll
        for (int nf = 0; nf < 2; ++nf) {
#pragma unroll
            for (int mf = 0; mf < 4; ++mf)
#pragma unroll
                for (int rg = 0; rg < 4; ++rg) {
                    float v = fmaf(-2.0f, acc[mf][nf][rg], sjv[nf]);
                    float vd = (li[mf][rg] == ljv[nf]) ? INFINITY : v;
                    n1[mf][rg] = fminf(n1[mf][rg], vd);
                }
        }
        // barrier at END: stage had the whole compute to land -> drain ~free
        __syncthreads();
    }

    // min across the 16 c-lanes sharing each accumulator row
#pragma unroll
    for (int m = 1; m < 16; m <<= 1) {
#pragma unroll
        for (int mf = 0; mf < 4; ++mf)
#pragma unroll
            for (int rg = 0; rg < 4; ++rg)
                n1[mf][rg] = fminf(n1[mf][rg], __shfl_xor(n1[mf][rg], m, 16));
    }
    if (c == 0) {
#pragma unroll
        for (int mf = 0; mf < 4; ++mf)
#pragma unroll
            for (int rg = 0; rg < 4; ++rg)
                part[g * BN + i0 + mf * 16 + q * 4 + rg] = n1[mf][rg];
    }
}

// combine 16 n1 slices + pos_d2 -> hinge; atomic sum; last block writes mean
__global__ __launch_bounds__(128) void merge_kernel(const float* __restrict__ part,
                                                    const float2* __restrict__ lsq,
                                                    const float* __restrict__ pos_d2,
                                                    float* __restrict__ g_acc,
                                                    unsigned* __restrict__ counter,
                                                    float* __restrict__ out) {
    int r = blockIdx.x * 128 + threadIdx.x;
    float n = INFINITY;
#pragma unroll
    for (int k = 0; k < 16; ++k) n = fminf(n, part[k * BN + r]);
    float si = lsq[r].x;
    float pos = sqrtf(fmaxf(pos_d2[r] + EPS_F, 0.f));
    float neg = sqrtf(fmaxf(si + n + EPS_F, 0.f));
    float h = fmaxf(MARGIN_F + pos - neg, 0.f);
    __shared__ float red[2];
#pragma unroll
    for (int m = 32; m >= 1; m >>= 1) h += __shfl_down(h, m, 64);
    if ((threadIdx.x & 63) == 0) red[threadIdx.x >> 6] = h;
    __syncthreads();
    if (threadIdx.x == 0) {
        atomicAdd(g_acc, red[0] + red[1]);
        __threadfence();
        unsigned old = atomicAdd(counter, 1u);
        if (old == 63u) {
            float tot = atomicAdd(g_acc, 0.0f);
            out[0] = tot / (float)BN;
        }
    }
}

extern "C" void kernel_launch(void* const* d_in, const int* in_sizes, int n_in,
                              void* d_out, int out_size, void* d_ws, size_t ws_size,
                              hipStream_t stream) {
    const float* f = (const float*)d_in[0];
    const int* lbl = (const int*)d_in[1];
    char* ws = (char*)d_ws;
    float2* lsq = (float2*)ws;                                 // 64 KB
    short8* fbT = (short8*)(ws + 65536);                       // 2 MB
    float* part = (float*)(ws + 65536 + 2097152);              // 512 KB (16 slices)
    float* pos_d2 = (float*)(ws + 65536 + 2097152 + 524288);   // 32 KB
    float* g_acc = (float*)(ws + 65536 + 2097152 + 524288 + 32768);
    unsigned* counter = (unsigned*)(g_acc + 1);
    float* out = (float*)d_out;

    prep_kernel<<<256, 256, 0, stream>>>(f, lbl, fbT, lsq, g_acc, counter);
    work_kernel<<<768, 256, 0, stream>>>(fbT, lbl, lsq, part, pos_d2);
    merge_kernel<<<64, 128, 0, stream>>>(part, lsq, pos_d2, g_acc, counter, out);
}